// Round 4
// baseline (323.473 us; speedup 1.0000x reference)
//
#include <hip/hip_runtime.h>

#define TT 6
#define D 128
#define KTOT 896           // 6*128 means + 128 x-slab
#define BM 64
#define BK 64
#define SCAN_BLK 2048
#define LN_EPS 1e-5f

typedef __bf16 bf16x8 __attribute__((ext_vector_type(8)));
typedef float f32x4 __attribute__((ext_vector_type(4)));

__device__ __forceinline__ unsigned short f2bf(float f) {
    unsigned int u = __float_as_uint(f);
    unsigned int r = (u + 0x7FFFu + ((u >> 16) & 1u)) >> 16;  // RNE
    return (unsigned short)r;
}

// XOR-swizzled LDS offset (elems): row-pitch 64, 8-elem groups swizzled by row&7
__device__ __forceinline__ int lds_off(int row, int kgrp) {
    return row * 64 + ((kgrp ^ (row & 7)) << 3);
}

// --- prep: WlT[n][t*128+k] = bf16(W_l[t][k][n]); slab t=6: sum_t W_r[t][k][n].
//     bias_total[o] = sum_t (b[t][o] + emb[t][o]).  Coalesced reads.
__global__ void prep_kernel(const float* __restrict__ W_l, const float* __restrict__ W_r,
                            const float* __restrict__ b, const float* __restrict__ emb,
                            unsigned short* __restrict__ WlT, float* __restrict__ bias_total) {
    int i = blockIdx.x * 256 + threadIdx.x;
    if (i < 6 * D * D) {
        int t = i >> 14, rem = i & 16383, k = rem >> 7, n = rem & 127;
        WlT[n * KTOT + t * D + k] = f2bf(W_l[i]);
    } else if (i < 7 * D * D) {
        int rem = i & 16383, k = rem >> 7, n = rem & 127;
        float s = 0.f;
#pragma unroll
        for (int tt = 0; tt < TT; ++tt) s += W_r[tt * D * D + rem];
        WlT[n * KTOT + TT * D + k] = f2bf(s);
    } else if (i < 7 * D * D + D) {
        int o = i - 7 * D * D;
        float s = 0.f;
#pragma unroll
        for (int t = 0; t < TT; ++t) s += b[t * D + o] + emb[t * D + o];
        bias_total[o] = s;
    }
}

__global__ void hist_kernel(const int* __restrict__ ei, const int* __restrict__ et,
                            int* __restrict__ hist, int E) {
    int e = blockIdx.x * 256 + threadIdx.x;
    if (e >= E) return;
    atomicAdd(&hist[ei[E + e] * TT + et[e]], 1);
}

__global__ void scan1_kernel(const int* __restrict__ in, int* __restrict__ out,
                             int* __restrict__ bsum, int S) {
    __shared__ int wsum[4];
    __shared__ int woff[4];
    int tid = threadIdx.x;
    int base = blockIdx.x * SCAN_BLK + tid * 8;
    int v[8];
    int ts = 0;
#pragma unroll
    for (int j = 0; j < 8; ++j) {
        v[j] = (base + j < S) ? in[base + j] : 0;
        ts += v[j];
    }
    int lane = tid & 63, wave = tid >> 6;
    int inc = ts;
#pragma unroll
    for (int o = 1; o < 64; o <<= 1) {
        int n = __shfl_up(inc, o);
        if (lane >= o) inc += n;
    }
    if (lane == 63) wsum[wave] = inc;
    __syncthreads();
    if (tid == 0) {
        int r = 0;
#pragma unroll
        for (int w = 0; w < 4; ++w) { int t = wsum[w]; woff[w] = r; r += t; }
        bsum[blockIdx.x] = r;
    }
    __syncthreads();
    int run = woff[wave] + inc - ts;
#pragma unroll
    for (int j = 0; j < 8; ++j) {
        if (base + j < S) out[base + j] = run;
        run += v[j];
    }
}

__global__ void scan3_kernel(int* __restrict__ off, int* __restrict__ cursor,
                             const int* __restrict__ bscan, int S, int E) {
    int tid = threadIdx.x;
    int base = blockIdx.x * SCAN_BLK + tid * 8;
    int add = bscan[blockIdx.x];
#pragma unroll
    for (int j = 0; j < 8; ++j) {
        int i = base + j;
        if (i < S) { int t = off[i] + add; off[i] = t; cursor[i] = t; }
    }
    if (blockIdx.x == 0 && tid == 0) off[S] = E;
}

__global__ void fill_kernel(const int* __restrict__ ei, const int* __restrict__ et,
                            int* __restrict__ cursor, int* __restrict__ sorted_src, int E) {
    int e = blockIdx.x * 256 + threadIdx.x;
    if (e >= E) return;
    int seg = ei[E + e] * TT + et[e];
    int pos = atomicAdd(&cursor[seg], 1);
    sorted_src[pos] = ei[e];
}

// --- aggregate: one HALF-WAVE (32 lanes, float4 each = full 128-col row) per task.
//     Pair (2p, 2p+1) is same node, adjacent types -> the wave's bf16 write is one
//     contiguous 512B store. Tasks [0,S): segment means. Then x-slab rows.
__global__ void aggregate_kernel(const float* __restrict__ x, const int* __restrict__ off,
                                 const int* __restrict__ sorted_src,
                                 unsigned short* __restrict__ A, int S, int N) {
    int wid = (blockIdx.x * blockDim.x + threadIdx.x) >> 6;   // pair id
    int lane = threadIdx.x & 63;
    int half = lane >> 5, l32 = lane & 31;
    int SP = S >> 1;                                          // S = N*6, even
    if (wid < SP) {
        int task = wid * 2 + half;
        int node = task / TT, t = task - node * TT;
        int e0 = off[task], e1 = off[task + 1];
        float4 a = make_float4(0.f, 0.f, 0.f, 0.f);
        int e = e0;
        while (e + 1 < e1) {
            int s0 = sorted_src[e], s1 = sorted_src[e + 1];
            float4 v0 = ((const float4*)(x + (size_t)s0 * D))[l32];
            float4 v1 = ((const float4*)(x + (size_t)s1 * D))[l32];
            a.x += v0.x + v1.x; a.y += v0.y + v1.y;
            a.z += v0.z + v1.z; a.w += v0.w + v1.w;
            e += 2;
        }
        if (e < e1) {
            float4 v0 = ((const float4*)(x + (size_t)sorted_src[e] * D))[l32];
            a.x += v0.x; a.y += v0.y; a.z += v0.z; a.w += v0.w;
        }
        int c = e1 - e0;
        if (c > 1) { float sc = 1.f / (float)c; a.x *= sc; a.y *= sc; a.z *= sc; a.w *= sc; }
        ushort4 p = make_ushort4(f2bf(a.x), f2bf(a.y), f2bf(a.z), f2bf(a.w));
        *(ushort4*)&A[(size_t)node * KTOT + t * D + 4 * l32] = p;
    } else {
        int node = (wid - SP) * 2 + half;
        if (node < N) {
            float4 v = ((const float4*)(x + (size_t)node * D))[l32];
            ushort4 p = make_ushort4(f2bf(v.x), f2bf(v.y), f2bf(v.z), f2bf(v.w));
            *(ushort4*)&A[(size_t)node * KTOT + TT * D + 4 * l32] = p;
        }
    }
}

// --- GEMM (M=Npad, K=896, N=128) bf16 MFMA + bias + LN + ReLU.  BM=64: 782 blocks
//     -> ~3 blocks/CU (12 waves/CU) for latency hiding; LDS 24KB; acc 32 VGPR/wave.
__launch_bounds__(256)
__global__ void gemm_ln_kernel(const unsigned short* __restrict__ A,
                               const unsigned short* __restrict__ WlT,
                               const float* __restrict__ bias_total,
                               const float* __restrict__ gamma, const float* __restrict__ beta,
                               float* __restrict__ out, int N) {
    __shared__ unsigned short As[BM * BK];   // swizzled [m][k]  8KB
    __shared__ unsigned short Bs[D * BK];    // swizzled [n][k] 16KB

    int tid = threadIdx.x;
    int lane = tid & 63, wave = tid >> 6;
    int q = lane >> 4, c16 = lane & 15;
    int blockRow = blockIdx.x * BM;

    f32x4 acc[8];
#pragma unroll
    for (int ct = 0; ct < 8; ++ct) acc[ct] = (f32x4){0.f, 0.f, 0.f, 0.f};

    uint4 a_reg[2], b_reg[4];
#pragma unroll
    for (int j = 0; j < 2; ++j) {
        int i = tid * 2 + j, row = i >> 3, kg = i & 7;
        int gr = blockRow + row; if (gr >= N) gr = N - 1;
        a_reg[j] = *(const uint4*)(A + (size_t)gr * KTOT + kg * 8);
    }
#pragma unroll
    for (int j = 0; j < 4; ++j) {
        int i = tid * 4 + j, row = i >> 3, kg = i & 7;
        b_reg[j] = *(const uint4*)(WlT + (size_t)row * KTOT + kg * 8);
    }

#pragma unroll 1
    for (int it = 0; it < KTOT / BK; ++it) {
        __syncthreads();
#pragma unroll
        for (int j = 0; j < 2; ++j) {
            int i = tid * 2 + j, row = i >> 3, kg = i & 7;
            *(uint4*)&As[lds_off(row, kg)] = a_reg[j];
        }
#pragma unroll
        for (int j = 0; j < 4; ++j) {
            int i = tid * 4 + j, row = i >> 3, kg = i & 7;
            *(uint4*)&Bs[lds_off(row, kg)] = b_reg[j];
        }
        __syncthreads();

        if (it + 1 < KTOT / BK) {
            int kk = (it + 1) * BK;
#pragma unroll
            for (int j = 0; j < 2; ++j) {
                int i = tid * 2 + j, row = i >> 3, kg = i & 7;
                int gr = blockRow + row; if (gr >= N) gr = N - 1;
                a_reg[j] = *(const uint4*)(A + (size_t)gr * KTOT + kk + kg * 8);
            }
#pragma unroll
            for (int j = 0; j < 4; ++j) {
                int i = tid * 4 + j, row = i >> 3, kg = i & 7;
                b_reg[j] = *(const uint4*)(WlT + (size_t)row * KTOT + kk + kg * 8);
            }
        }

#pragma unroll
        for (int ks = 0; ks < 2; ++ks) {
            int kgrp = ks * 4 + q;
            bf16x8 af = *(const bf16x8*)&As[lds_off(wave * 16 + c16, kgrp)];
#pragma unroll
            for (int ct = 0; ct < 8; ++ct) {
                bf16x8 bfr = *(const bf16x8*)&Bs[lds_off(ct * 16 + c16, kgrp)];
                acc[ct] = __builtin_amdgcn_mfma_f32_16x16x32_bf16(af, bfr, acc[ct], 0, 0, 0);
            }
        }
    }

    // epilogue: bias + LayerNorm + ReLU
    float bias_c[8], g_c[8], bt_c[8];
#pragma unroll
    for (int ct = 0; ct < 8; ++ct) {
        int col = ct * 16 + c16;
        bias_c[ct] = bias_total[col];
        g_c[ct] = gamma[col];
        bt_c[ct] = beta[col];
    }
#pragma unroll
    for (int reg = 0; reg < 4; ++reg) {
        float h[8];
        float s = 0.f, s2 = 0.f;
#pragma unroll
        for (int ct = 0; ct < 8; ++ct) {
            h[ct] = acc[ct][reg] + bias_c[ct];
            s += h[ct];
            s2 += h[ct] * h[ct];
        }
#pragma unroll
        for (int o = 8; o >= 1; o >>= 1) {
            s  += __shfl_xor(s, o, 16);
            s2 += __shfl_xor(s2, o, 16);
        }
        float mu = s * (1.f / 128.f);
        float var = s2 * (1.f / 128.f) - mu * mu;
        float rstd = rsqrtf(var + LN_EPS);
        int row = blockRow + wave * 16 + q * 4 + reg;
        if (row < N) {
#pragma unroll
            for (int ct = 0; ct < 8; ++ct) {
                float y = (h[ct] - mu) * rstd * g_c[ct] + bt_c[ct];
                out[(size_t)row * D + ct * 16 + c16] = fmaxf(y, 0.f);
            }
        }
    }
}

extern "C" void kernel_launch(void* const* d_in, const int* in_sizes, int n_in,
                              void* d_out, int out_size, void* d_ws, size_t ws_size,
                              hipStream_t stream) {
    const float* x     = (const float*)d_in[0];
    const int*   ei    = (const int*)d_in[1];
    const int*   et    = (const int*)d_in[2];
    const float* W_l   = (const float*)d_in[3];
    const float* W_r   = (const float*)d_in[4];
    const float* b     = (const float*)d_in[5];
    const float* emb   = (const float*)d_in[6];
    const float* gamma = (const float*)d_in[7];
    const float* beta  = (const float*)d_in[8];

    int N = in_sizes[0] / D;
    int E = in_sizes[2];
    int S = N * TT;
    int NB = (S + SCAN_BLK - 1) / SCAN_BLK;
    int NBLK = (N + BM - 1) / BM;
    int Npad = NBLK * BM;

    // workspace carve
    int* hist       = (int*)d_ws;            // S
    int* off        = hist + S;              // S+1
    int* cursor     = off + S + 1;           // S
    int* bsum       = cursor + S;            // NB
    int* bscan      = bsum + NB;             // NB
    int* dummy      = bscan + NB;            // 1
    int* sorted_src = dummy + 1;             // E
    size_t ofs = (size_t)((char*)(sorted_src + E) - (char*)d_ws);
    ofs = (ofs + 15) & ~(size_t)15;
    unsigned short* WlT = (unsigned short*)((char*)d_ws + ofs);   // 128*896
    float* bias_total = (float*)(WlT + D * KTOT);                 // 128
    size_t ofs2 = (size_t)((char*)(bias_total + D) - (char*)d_ws);
    ofs2 = (ofs2 + 15) & ~(size_t)15;
    unsigned short* Abuf = (unsigned short*)((char*)d_ws + ofs2); // Npad*896

    hipMemsetAsync(hist, 0, (size_t)S * sizeof(int), stream);

    int prep_total = 7 * D * D + D;
    prep_kernel<<<(prep_total + 255) / 256, 256, 0, stream>>>(W_l, W_r, b, emb, WlT, bias_total);

    hist_kernel<<<(E + 255) / 256, 256, 0, stream>>>(ei, et, hist, E);
    scan1_kernel<<<NB, 256, 0, stream>>>(hist, off, bsum, S);
    scan1_kernel<<<1, 256, 0, stream>>>(bsum, bscan, dummy, NB);
    scan3_kernel<<<NB, 256, 0, stream>>>(off, cursor, bscan, S, E);
    fill_kernel<<<(E + 255) / 256, 256, 0, stream>>>(ei, et, cursor, sorted_src, E);

    int pairs = S / 2 + (N + 1) / 2;
    aggregate_kernel<<<(pairs + 3) / 4, 256, 0, stream>>>(x, off, sorted_src, Abuf, S, N);

    gemm_ln_kernel<<<NBLK, 256, 0, stream>>>(Abuf, WlT, bias_total, gamma, beta,
                                             (float*)d_out, N);
}

// Round 5
// 296.174 us; speedup vs baseline: 1.0922x; 1.0922x over previous
//
#include <hip/hip_runtime.h>

#define TT 6
#define D 128
#define KTOT 896           // 6*128 means + 128 x-slab
#define BM 128
#define SCAN_BLK 2048
#define LN_EPS 1e-5f

typedef __bf16 bf16x8 __attribute__((ext_vector_type(8)));
typedef float f32x4 __attribute__((ext_vector_type(4)));

__device__ __forceinline__ unsigned short f2bf(float f) {
    unsigned int u = __float_as_uint(f);
    unsigned int r = (u + 0x7FFFu + ((u >> 16) & 1u)) >> 16;  // RNE
    return (unsigned short)r;
}

// XOR-swizzled LDS offset (ushort elems) for 128-elem rows: 16 chunks of 8.
// Conflict-free for both the quarter-wave agg stores and the MFMA frag reads.
__device__ __forceinline__ int lds_off128(int row, int kgrp) {
    return row * 128 + (((kgrp & 7) ^ (row & 7)) | (kgrp & 8)) * 8;
}

// --- prep: WlT[n][t*128+k] = bf16(W_l[t][k][n]); slab 6: sum_t W_r[t][k][n].
__global__ void prep_kernel(const float* __restrict__ W_l, const float* __restrict__ W_r,
                            const float* __restrict__ b, const float* __restrict__ emb,
                            unsigned short* __restrict__ WlT, float* __restrict__ bias_total) {
    int i = blockIdx.x * 256 + threadIdx.x;
    if (i < 6 * D * D) {
        int t = i >> 14, rem = i & 16383, k = rem >> 7, n = rem & 127;
        WlT[n * KTOT + t * D + k] = f2bf(W_l[i]);
    } else if (i < 7 * D * D) {
        int rem = i & 16383, k = rem >> 7, n = rem & 127;
        float s = 0.f;
#pragma unroll
        for (int tt = 0; tt < TT; ++tt) s += W_r[tt * D * D + rem];
        WlT[n * KTOT + TT * D + k] = f2bf(s);
    } else if (i < 7 * D * D + D) {
        int o = i - 7 * D * D;
        float s = 0.f;
#pragma unroll
        for (int t = 0; t < TT; ++t) s += b[t * D + o] + emb[t * D + o];
        bias_total[o] = s;
    }
}

// --- cast x (fp32) -> xb (bf16). 12.8 MB result, L2-friendly gather target.
__global__ void cast_kernel(const float* __restrict__ x, unsigned short* __restrict__ xb,
                            int total8) {
    int i = blockIdx.x * 256 + threadIdx.x;
    if (i >= total8) return;
    const float4* p = (const float4*)x + (size_t)i * 2;
    float4 a = p[0], bb = p[1];
    uint4 o;
    o.x = (unsigned int)f2bf(a.x) | ((unsigned int)f2bf(a.y) << 16);
    o.y = (unsigned int)f2bf(a.z) | ((unsigned int)f2bf(a.w) << 16);
    o.z = (unsigned int)f2bf(bb.x) | ((unsigned int)f2bf(bb.y) << 16);
    o.w = (unsigned int)f2bf(bb.z) | ((unsigned int)f2bf(bb.w) << 16);
    ((uint4*)xb)[i] = o;
}

__global__ void hist_kernel(const int* __restrict__ ei, const int* __restrict__ et,
                            int* __restrict__ hist, int E) {
    int e = blockIdx.x * 256 + threadIdx.x;
    if (e >= E) return;
    atomicAdd(&hist[ei[E + e] * TT + et[e]], 1);
}

__global__ void scan1_kernel(const int* __restrict__ in, int* __restrict__ out,
                             int* __restrict__ bsum, int S) {
    __shared__ int wsum[4];
    __shared__ int woff[4];
    int tid = threadIdx.x;
    int base = blockIdx.x * SCAN_BLK + tid * 8;
    int v[8];
    int ts = 0;
#pragma unroll
    for (int j = 0; j < 8; ++j) {
        v[j] = (base + j < S) ? in[base + j] : 0;
        ts += v[j];
    }
    int lane = tid & 63, wave = tid >> 6;
    int inc = ts;
#pragma unroll
    for (int o = 1; o < 64; o <<= 1) {
        int n = __shfl_up(inc, o);
        if (lane >= o) inc += n;
    }
    if (lane == 63) wsum[wave] = inc;
    __syncthreads();
    if (tid == 0) {
        int r = 0;
#pragma unroll
        for (int w = 0; w < 4; ++w) { int t = wsum[w]; woff[w] = r; r += t; }
        bsum[blockIdx.x] = r;
    }
    __syncthreads();
    int run = woff[wave] + inc - ts;
#pragma unroll
    for (int j = 0; j < 8; ++j) {
        if (base + j < S) out[base + j] = run;
        run += v[j];
    }
}

__global__ void scan3_kernel(int* __restrict__ off, int* __restrict__ cursor,
                             const int* __restrict__ bscan, int S, int E) {
    int tid = threadIdx.x;
    int base = blockIdx.x * SCAN_BLK + tid * 8;
    int add = bscan[blockIdx.x];
#pragma unroll
    for (int j = 0; j < 8; ++j) {
        int i = base + j;
        if (i < S) { int t = off[i] + add; off[i] = t; cursor[i] = t; }
    }
    if (blockIdx.x == 0 && tid == 0) off[S] = E;
}

__global__ void fill_kernel(const int* __restrict__ ei, const int* __restrict__ et,
                            int* __restrict__ cursor, int* __restrict__ sorted_src, int E) {
    int e = blockIdx.x * 256 + threadIdx.x;
    if (e >= E) return;
    int seg = ei[E + e] * TT + et[e];
    int pos = atomicAdd(&cursor[seg], 1);
    sorted_src[pos] = ei[e];
}

// --- fused: in-LDS mean aggregation (16 quarter-waves in parallel) -> bf16 MFMA
//     over 7 K-slabs -> bias + LayerNorm + ReLU. No intermediate A buffer.
__launch_bounds__(256, 2)
__global__ void fused_kernel(const unsigned short* __restrict__ xb,
                             const int* __restrict__ off, const int* __restrict__ sorted_src,
                             const unsigned short* __restrict__ WlT,
                             const float* __restrict__ bias_total,
                             const float* __restrict__ gamma, const float* __restrict__ beta,
                             float* __restrict__ out, int N, int S) {
    __shared__ unsigned short As[BM * 128];   // 32 KB swizzled A slab [m][k]
    __shared__ unsigned short Bs[D * 128];    // 32 KB swizzled B slab [n][k]
    __shared__ int offs[BM * TT + 1];         // segment offsets for this block's nodes

    int tid = threadIdx.x;
    int lane = tid & 63, wave = tid >> 6;
    int q = lane >> 4, c16 = lane & 15;
    int qid = tid >> 4, l16 = tid & 15;       // 16 quarters x 16 lanes
    int blockRow = blockIdx.x * BM;

    // preload this block's CSR offsets (769 ints, coalesced)
    for (int i = tid; i <= BM * TT; i += 256) {
        int g = blockRow * TT + i;
        if (g > S) g = S;
        offs[i] = off[g];
    }

    f32x4 acc[2][8];
#pragma unroll
    for (int rt = 0; rt < 2; ++rt)
#pragma unroll
        for (int ct = 0; ct < 8; ++ct) acc[rt][ct] = (f32x4){0.f, 0.f, 0.f, 0.f};

    __syncthreads();   // offs ready

#pragma unroll 1
    for (int t = 0; t < 7; ++t) {
        // issue B-slab global loads early (no LDS dependency)
        uint4 b_reg[8];
#pragma unroll
        for (int j = 0; j < 8; ++j) {
            int idx = j * 256 + tid, row = idx >> 4, kg = idx & 15;
            b_reg[j] = *(const uint4*)(WlT + (size_t)row * KTOT + t * D + kg * 8);
        }

        __syncthreads();   // previous MFMA frag reads complete

        if (t < TT) {
            // aggregate 8 segments per quarter into swizzled As
#pragma unroll 1
            for (int i = 0; i < 8; ++i) {
                int row = qid * 8 + i;
                int oi = row * TT + t;
                int e0 = offs[oi], e1 = offs[oi + 1];
                float a0 = 0.f, a1 = 0.f, a2 = 0.f, a3 = 0.f;
                float a4 = 0.f, a5 = 0.f, a6 = 0.f, a7 = 0.f;
                int e = e0;
                while (e + 1 < e1) {
                    int s0 = sorted_src[e], s1 = sorted_src[e + 1];
                    uint4 v0 = *(const uint4*)(xb + (size_t)s0 * D + l16 * 8);
                    uint4 v1 = *(const uint4*)(xb + (size_t)s1 * D + l16 * 8);
                    a0 += __uint_as_float(v0.x << 16) + __uint_as_float(v1.x << 16);
                    a1 += __uint_as_float(v0.x & 0xffff0000u) + __uint_as_float(v1.x & 0xffff0000u);
                    a2 += __uint_as_float(v0.y << 16) + __uint_as_float(v1.y << 16);
                    a3 += __uint_as_float(v0.y & 0xffff0000u) + __uint_as_float(v1.y & 0xffff0000u);
                    a4 += __uint_as_float(v0.z << 16) + __uint_as_float(v1.z << 16);
                    a5 += __uint_as_float(v0.z & 0xffff0000u) + __uint_as_float(v1.z & 0xffff0000u);
                    a6 += __uint_as_float(v0.w << 16) + __uint_as_float(v1.w << 16);
                    a7 += __uint_as_float(v0.w & 0xffff0000u) + __uint_as_float(v1.w & 0xffff0000u);
                    e += 2;
                }
                if (e < e1) {
                    int s0 = sorted_src[e];
                    uint4 v0 = *(const uint4*)(xb + (size_t)s0 * D + l16 * 8);
                    a0 += __uint_as_float(v0.x << 16);
                    a1 += __uint_as_float(v0.x & 0xffff0000u);
                    a2 += __uint_as_float(v0.y << 16);
                    a3 += __uint_as_float(v0.y & 0xffff0000u);
                    a4 += __uint_as_float(v0.z << 16);
                    a5 += __uint_as_float(v0.z & 0xffff0000u);
                    a6 += __uint_as_float(v0.w << 16);
                    a7 += __uint_as_float(v0.w & 0xffff0000u);
                }
                int c = e1 - e0;
                if (c > 1) {
                    float sc = 1.f / (float)c;
                    a0 *= sc; a1 *= sc; a2 *= sc; a3 *= sc;
                    a4 *= sc; a5 *= sc; a6 *= sc; a7 *= sc;
                }
                uint4 p;
                p.x = (unsigned int)f2bf(a0) | ((unsigned int)f2bf(a1) << 16);
                p.y = (unsigned int)f2bf(a2) | ((unsigned int)f2bf(a3) << 16);
                p.z = (unsigned int)f2bf(a4) | ((unsigned int)f2bf(a5) << 16);
                p.w = (unsigned int)f2bf(a6) | ((unsigned int)f2bf(a7) << 16);
                *(uint4*)&As[lds_off128(row, l16)] = p;
            }
        } else {
            // x-slab: direct bf16 copy of this block's rows
#pragma unroll
            for (int j = 0; j < 8; ++j) {
                int idx = j * 256 + tid, row = idx >> 4, kg = idx & 15;
                int gr = blockRow + row;
                if (gr >= N) gr = N - 1;
                uint4 v = *(const uint4*)(xb + (size_t)gr * D + kg * 8);
                *(uint4*)&As[lds_off128(row, kg)] = v;
            }
        }

        // stage B slab (loads issued before the agg phase -> long since landed)
#pragma unroll
        for (int j = 0; j < 8; ++j) {
            int idx = j * 256 + tid, row = idx >> 4, kg = idx & 15;
            *(uint4*)&Bs[lds_off128(row, kg)] = b_reg[j];
        }
        __syncthreads();

        // MFMA: K=128 in 4 steps of 32
#pragma unroll
        for (int ks = 0; ks < 4; ++ks) {
            int kgrp = ks * 4 + q;
            bf16x8 af0 = *(const bf16x8*)&As[lds_off128(wave * 32 + c16, kgrp)];
            bf16x8 af1 = *(const bf16x8*)&As[lds_off128(wave * 32 + 16 + c16, kgrp)];
#pragma unroll
            for (int ct = 0; ct < 8; ++ct) {
                bf16x8 bfr = *(const bf16x8*)&Bs[lds_off128(ct * 16 + c16, kgrp)];
                acc[0][ct] = __builtin_amdgcn_mfma_f32_16x16x32_bf16(af0, bfr, acc[0][ct], 0, 0, 0);
                acc[1][ct] = __builtin_amdgcn_mfma_f32_16x16x32_bf16(af1, bfr, acc[1][ct], 0, 0, 0);
            }
        }
    }

    // epilogue: bias + LayerNorm + ReLU
    float bias_c[8], g_c[8], bt_c[8];
#pragma unroll
    for (int ct = 0; ct < 8; ++ct) {
        int col = ct * 16 + c16;
        bias_c[ct] = bias_total[col];
        g_c[ct] = gamma[col];
        bt_c[ct] = beta[col];
    }
#pragma unroll
    for (int rt = 0; rt < 2; ++rt) {
#pragma unroll
        for (int reg = 0; reg < 4; ++reg) {
            float h[8];
            float s = 0.f, s2 = 0.f;
#pragma unroll
            for (int ct = 0; ct < 8; ++ct) {
                h[ct] = acc[rt][ct][reg] + bias_c[ct];
                s += h[ct];
                s2 += h[ct] * h[ct];
            }
#pragma unroll
            for (int o = 8; o >= 1; o >>= 1) {
                s  += __shfl_xor(s, o, 16);
                s2 += __shfl_xor(s2, o, 16);
            }
            float mu = s * (1.f / 128.f);
            float var = s2 * (1.f / 128.f) - mu * mu;
            float rstd = rsqrtf(var + LN_EPS);
            int row = blockRow + wave * 32 + rt * 16 + q * 4 + reg;
            if (row < N) {
#pragma unroll
                for (int ct = 0; ct < 8; ++ct) {
                    float y = (h[ct] - mu) * rstd * g_c[ct] + bt_c[ct];
                    out[(size_t)row * D + ct * 16 + c16] = fmaxf(y, 0.f);
                }
            }
        }
    }
}

extern "C" void kernel_launch(void* const* d_in, const int* in_sizes, int n_in,
                              void* d_out, int out_size, void* d_ws, size_t ws_size,
                              hipStream_t stream) {
    const float* x     = (const float*)d_in[0];
    const int*   ei    = (const int*)d_in[1];
    const int*   et    = (const int*)d_in[2];
    const float* W_l   = (const float*)d_in[3];
    const float* W_r   = (const float*)d_in[4];
    const float* b     = (const float*)d_in[5];
    const float* emb   = (const float*)d_in[6];
    const float* gamma = (const float*)d_in[7];
    const float* beta  = (const float*)d_in[8];

    int N = in_sizes[0] / D;
    int E = in_sizes[2];
    int S = N * TT;
    int NB = (S + SCAN_BLK - 1) / SCAN_BLK;
    int NBLK = (N + BM - 1) / BM;

    // workspace carve
    int* hist       = (int*)d_ws;            // S
    int* off        = hist + S;              // S+1
    int* cursor     = off + S + 1;           // S
    int* bsum       = cursor + S;            // NB
    int* bscan      = bsum + NB;             // NB
    int* dummy      = bscan + NB;            // 1
    int* sorted_src = dummy + 1;             // E
    size_t ofs = (size_t)((char*)(sorted_src + E) - (char*)d_ws);
    ofs = (ofs + 15) & ~(size_t)15;
    unsigned short* WlT = (unsigned short*)((char*)d_ws + ofs);   // 128*896
    float* bias_total = (float*)(WlT + D * KTOT);                 // 128
    size_t ofs2 = (size_t)((char*)(bias_total + D) - (char*)d_ws);
    ofs2 = (ofs2 + 15) & ~(size_t)15;
    unsigned short* xb = (unsigned short*)((char*)d_ws + ofs2);   // N*128 bf16

    hipMemsetAsync(hist, 0, (size_t)S * sizeof(int), stream);

    int prep_total = 7 * D * D + D;
    prep_kernel<<<(prep_total + 255) / 256, 256, 0, stream>>>(W_l, W_r, b, emb, WlT, bias_total);

    int total8 = N * D / 8;
    cast_kernel<<<(total8 + 255) / 256, 256, 0, stream>>>(x, xb, total8);

    hist_kernel<<<(E + 255) / 256, 256, 0, stream>>>(ei, et, hist, E);
    scan1_kernel<<<NB, 256, 0, stream>>>(hist, off, bsum, S);
    scan1_kernel<<<1, 256, 0, stream>>>(bsum, bscan, dummy, NB);
    scan3_kernel<<<NB, 256, 0, stream>>>(off, cursor, bscan, S, E);
    fill_kernel<<<(E + 255) / 256, 256, 0, stream>>>(ei, et, cursor, sorted_src, E);

    fused_kernel<<<NBLK, 256, 0, stream>>>(xb, off, sorted_src, WlT, bias_total,
                                           gamma, beta, (float*)d_out, N, S);
}